// Round 1
// baseline (40.462 us; speedup 1.0000x reference)
//
#include <hip/hip_runtime.h>

#define NQ   10
#define DIM  1024
#define NL   4
#define NCL  10
#define PI_F 3.14159265358979f

// Composite CNOT-chain permutation: Q(d)_j = d_j ^ d_{j-1} (j>=1), Q(d)_0 = d_0
__device__ __forceinline__ int permQ(int d) {
    return d ^ ((d & 0x1FF) << 1);
}

__global__ __launch_bounds__(256)
void qnn_kernel(const float* __restrict__ x,
                const float* __restrict__ W_pre,
                const float* __restrict__ b_pre,
                const float* __restrict__ weights,
                const float* __restrict__ W_post,
                const float* __restrict__ b_post,
                float* __restrict__ out)
{
    __shared__ float reA[DIM], imA[DIM], reB[DIM], imB[DIM];
    __shared__ float hS[NQ], zzS[NQ - 1];
    __shared__ float csC[(NL + 1) * NQ], csS[(NL + 1) * NQ];
    __shared__ float wq[4][NCL], qf[NCL];

    const int t = threadIdx.x;
    const int b = blockIdx.x;

    // h = x @ W_pre.T + b_pre  (per-block, 10 dot products of length 10)
    if (t < NQ) {
        float acc = b_pre[t];
        #pragma unroll
        for (int k = 0; k < NQ; ++k)
            acc = fmaf(x[b * NQ + k], W_pre[t * NQ + k], acc);
        hS[t] = acc;
    }
    // half-angle cos/sin table (same for all blocks; trivial)
    if (t >= 64 && t < 64 + (NL + 1) * NQ) {
        int i = t - 64;
        float th = 0.5f * weights[i];
        csC[i] = cosf(th);
        csS[i] = sinf(th);
    }
    __syncthreads();
    if (t < NQ - 1)
        zzS[t] = (PI_F - hS[t]) * (PI_F - hS[t + 1]);
    __syncthreads();

    float hr[NQ], zr[NQ - 1];
    #pragma unroll
    for (int i = 0; i < NQ; ++i) hr[i] = hS[i];
    #pragma unroll
    for (int i = 0; i < NQ - 1; ++i) zr[i] = zzS[i];

    // state init: (1/32) * exp(-i*ang(d))
    #pragma unroll
    for (int j = 0; j < 4; ++j) {
        int d = t + 256 * j;
        float ang = 0.0f;
        #pragma unroll
        for (int i = 0; i < NQ; ++i)
            ang += ((d >> i) & 1) ? -hr[i] : hr[i];
        #pragma unroll
        for (int i = 0; i < NQ - 1; ++i)
            ang += (((d >> i) ^ (d >> (i + 1))) & 1) ? -zr[i] : zr[i];
        float sn, cn;
        __sincosf(ang, &sn, &cn);
        reA[d] = 0.03125f * cn;
        imA[d] = -0.03125f * sn;
    }
    __syncthreads();

    float* rs = reA; float* is_ = imA;
    float* rd = reB; float* id_ = imB;

    for (int l = 0; l <= NL; ++l) {
        #pragma unroll
        for (int wp = 0; wp < 5; ++wp) {
            const int w  = 2 * wp;
            const float c0 = csC[l * NQ + w],     s0 = csS[l * NQ + w];
            const float c1 = csC[l * NQ + w + 1], s1 = csS[l * NQ + w + 1];
            const int base = ((t >> w) << (w + 2)) | (t & ((1 << w) - 1));
            const bool doPerm = (l > 0) && (wp == 0);

            // quadrant visit rotation to kill LDS bank conflicts
            int rot;
            if (wp <= 1)      rot = (t >> 3) & 3;
            else if (wp == 2) rot = (t >> 4) & 3;
            else              rot = 0;

            float ar[4], ai[4];
            if (wp == 0 && !doPerm) {
                float4 rv = *reinterpret_cast<const float4*>(&rs[base]);
                float4 iv = *reinterpret_cast<const float4*>(&is_[base]);
                ar[0] = rv.x; ar[1] = rv.y; ar[2] = rv.z; ar[3] = rv.w;
                ai[0] = iv.x; ai[1] = iv.y; ai[2] = iv.z; ai[3] = iv.w;
            } else {
                #pragma unroll
                for (int k = 0; k < 4; ++k) {
                    int q = k ^ rot;
                    int d = base | (q << w);
                    int sidx = doPerm ? permQ(d) : d;
                    ar[q] = rs[sidx];
                    ai[q] = is_[sidx];
                }
            }

            // RY(w): mixes quadrants differing in bit w -> pairs (0,1),(2,3)
            {
                float n0 = c0 * ar[0] - s0 * ar[1];
                float n1 = s0 * ar[0] + c0 * ar[1];
                float n2 = c0 * ar[2] - s0 * ar[3];
                float n3 = s0 * ar[2] + c0 * ar[3];
                ar[0] = n0; ar[1] = n1; ar[2] = n2; ar[3] = n3;
                float m0 = c0 * ai[0] - s0 * ai[1];
                float m1 = s0 * ai[0] + c0 * ai[1];
                float m2 = c0 * ai[2] - s0 * ai[3];
                float m3 = s0 * ai[2] + c0 * ai[3];
                ai[0] = m0; ai[1] = m1; ai[2] = m2; ai[3] = m3;
            }
            // RY(w+1): pairs (0,2),(1,3)
            {
                float n0 = c1 * ar[0] - s1 * ar[2];
                float n2 = s1 * ar[0] + c1 * ar[2];
                float n1 = c1 * ar[1] - s1 * ar[3];
                float n3 = s1 * ar[1] + c1 * ar[3];
                ar[0] = n0; ar[1] = n1; ar[2] = n2; ar[3] = n3;
                float m0 = c1 * ai[0] - s1 * ai[2];
                float m2 = s1 * ai[0] + c1 * ai[2];
                float m1 = c1 * ai[1] - s1 * ai[3];
                float m3 = s1 * ai[1] + c1 * ai[3];
                ai[0] = m0; ai[1] = m1; ai[2] = m2; ai[3] = m3;
            }

            if (wp == 0) {
                *reinterpret_cast<float4*>(&rd[base]) = make_float4(ar[0], ar[1], ar[2], ar[3]);
                *reinterpret_cast<float4*>(&id_[base]) = make_float4(ai[0], ai[1], ai[2], ai[3]);
            } else {
                #pragma unroll
                for (int k = 0; k < 4; ++k) {
                    int q = k ^ rot;
                    int d = base | (q << w);
                    rd[d] = ar[q];
                    id_[d] = ai[q];
                }
            }
            __syncthreads();
            float* tr = rs; rs = rd; rd = tr;
            float* ti = is_; is_ = id_; id_ = ti;
        }
    }

    // probs -> q_k = sum_d p(d) * sign_k(d)
    float qk[NCL];
    #pragma unroll
    for (int k = 0; k < NCL; ++k) qk[k] = 0.0f;
    #pragma unroll
    for (int j = 0; j < 4; ++j) {
        int d = t + 256 * j;
        float pr = rs[d], pi = is_[d];
        float p = pr * pr + pi * pi;
        #pragma unroll
        for (int k = 0; k < NCL; ++k)
            qk[k] += ((d >> k) & 1) ? -p : p;
    }
    const int lane = t & 63, wv = t >> 6;
    #pragma unroll
    for (int k = 0; k < NCL; ++k) {
        float v = qk[k];
        #pragma unroll
        for (int off = 32; off > 0; off >>= 1)
            v += __shfl_down(v, off);
        if (lane == 0) wq[wv][k] = v;
    }
    __syncthreads();
    if (t < NCL) qf[t] = wq[0][t] + wq[1][t] + wq[2][t] + wq[3][t];
    __syncthreads();
    if (t < NCL) {
        float o = b_post[t];
        #pragma unroll
        for (int k = 0; k < NCL; ++k)
            o = fmaf(qf[k], W_post[t * NQ + k], o);
        out[b * NCL + t] = o;
    }
}

extern "C" void kernel_launch(void* const* d_in, const int* in_sizes, int n_in,
                              void* d_out, int out_size, void* d_ws, size_t ws_size,
                              hipStream_t stream) {
    const float* x       = (const float*)d_in[0];
    const float* W_pre   = (const float*)d_in[1];
    const float* b_pre   = (const float*)d_in[2];
    const float* weights = (const float*)d_in[3];
    const float* W_post  = (const float*)d_in[4];
    const float* b_post  = (const float*)d_in[5];
    float* outp = (float*)d_out;
    int batch = in_sizes[0] / NQ;
    qnn_kernel<<<batch, 256, 0, stream>>>(x, W_pre, b_pre, weights, W_post, b_post, outp);
}

// Round 4
// 34.593 us; speedup vs baseline: 1.1697x; 1.1697x over previous
//
#include <hip/hip_runtime.h>

#define NQ   10
#define NL   4
#define NCL  10
#define PI_F 3.14159265358979f

// Layout: one wave (64 lanes) per batch element.
// Lane l holds the 16 complex amplitudes with index d = (l<<4) | r,
// i.e. register bits = qubits 0..3, lane bits = qubits 4..9.
__global__ __launch_bounds__(256)
void qnn_kernel(const float* __restrict__ x,
                const float* __restrict__ W_pre,
                const float* __restrict__ b_pre,
                const float* __restrict__ weights,
                const float* __restrict__ W_post,
                const float* __restrict__ b_post,
                float* __restrict__ out, int batch)
{
    const int lane = threadIdx.x & 63;
    const int b = blockIdx.x * 4 + (threadIdx.x >> 6);
    if (b >= batch) return;

    // 50 half-angle cos/sin pairs: lane j<50 owns weight j, broadcast later.
    float cw = 0.0f, sw = 0.0f;
    if (lane < (NL + 1) * NQ) {
        float th = 0.5f * weights[lane];
        sincosf(th, &sw, &cw);   // one-time, precise
    }

    // h = x @ W_pre.T + b_pre : lane j<10 computes h_j, then broadcast.
    float hval = 0.0f;
    if (lane < NQ) {
        hval = b_pre[lane];
        #pragma unroll
        for (int k = 0; k < NQ; ++k)
            hval = fmaf(x[b * NQ + k], W_pre[lane * NQ + k], hval);
    }
    float h[NQ];
    #pragma unroll
    for (int i = 0; i < NQ; ++i) h[i] = __shfl(hval, i);
    float z[NQ - 1];
    #pragma unroll
    for (int i = 0; i < NQ - 1; ++i) z[i] = (PI_F - h[i]) * (PI_F - h[i + 1]);

    // State init: (1/32) * exp(-i*ang(d)).
    // ang = lane-part A + register-part + cross zz-term (qubits 3,4).
    float A = 0.0f;
    #pragma unroll
    for (int i = 4; i < NQ; ++i)
        A += ((lane >> (i - 4)) & 1) ? -h[i] : h[i];
    #pragma unroll
    for (int i = 4; i < NQ - 1; ++i)
        A += (((lane >> (i - 4)) ^ (lane >> (i - 3))) & 1) ? -z[i] : z[i];

    float sr[16], si[16];
    #pragma unroll
    for (int r = 0; r < 16; ++r) {
        float ang = A;
        #pragma unroll
        for (int i = 0; i < 4; ++i)
            ang += ((r >> i) & 1) ? -h[i] : h[i];
        #pragma unroll
        for (int i = 0; i < 3; ++i)
            ang += (((r >> i) ^ (r >> (i + 1))) & 1) ? -z[i] : z[i];
        ang += (((r >> 3) ^ lane) & 1) ? -z[3] : z[3];  // zz pair (3,4)
        float sn, cn;
        __sincosf(ang, &sn, &cn);
        sr[r] = 0.03125f * cn;
        si[r] = -0.03125f * sn;
    }

    // Composite CNOT-chain perm, lane part: l' = ((l ^ (l<<1)) & 0x3F) ^ r3
    const int plbase = (lane ^ (lane << 1)) & 0x3F;

    for (int l = 0; l <= NL; ++l) {
        if (l > 0) {
            // new[(l,r)] = old[(l', r')], r' = (r ^ (r<<1)) & 0xF
            float nr[16], ni[16];
            #pragma unroll
            for (int r = 0; r < 16; ++r) {
                const int rp = (r ^ (r << 1)) & 0xF;
                const int sl = plbase ^ (r >> 3);
                nr[r] = __shfl(sr[rp], sl);
                ni[r] = __shfl(si[rp], sl);
            }
            #pragma unroll
            for (int r = 0; r < 16; ++r) { sr[r] = nr[r]; si[r] = ni[r]; }
        }

        // RY on wires 0..3: pure in-register butterflies.
        #pragma unroll
        for (int w = 0; w < 4; ++w) {
            const float c = __shfl(cw, l * NQ + w);
            const float s = __shfl(sw, l * NQ + w);
            #pragma unroll
            for (int r = 0; r < 16; ++r) {
                if (r & (1 << w)) continue;
                const int q = r | (1 << w);
                float a0 = sr[r], a1 = sr[q];
                sr[r] = fmaf(c, a0, -(s * a1));
                sr[q] = fmaf(s, a0, c * a1);
                float b0 = si[r], b1 = si[q];
                si[r] = fmaf(c, b0, -(s * b1));
                si[q] = fmaf(s, b0, c * b1);
            }
        }

        // RY on wires 4..9: lane-bit butterflies via shfl_xor.
        // new = c*own + s_eff*partner, s_eff = own_bit ? +s : -s.
        #pragma unroll
        for (int w = 4; w < NQ; ++w) {
            const float c = __shfl(cw, l * NQ + w);
            const float s = __shfl(sw, l * NQ + w);
            const int m = 1 << (w - 4);
            const float se = (lane & m) ? s : -s;
            #pragma unroll
            for (int r = 0; r < 16; ++r) {
                float tr = __shfl_xor(sr[r], m);
                sr[r] = fmaf(c, sr[r], se * tr);
                float ti = __shfl_xor(si[r], m);
                si[r] = fmaf(c, si[r], se * ti);
            }
        }
    }

    // q_k = sum_d p(d) * (1 - 2*bit_k(d)); 10 per-lane partials, butterfly-reduce.
    float P = 0.0f;
    float pk[NCL];
    #pragma unroll
    for (int k = 0; k < 4; ++k) pk[k] = 0.0f;
    #pragma unroll
    for (int r = 0; r < 16; ++r) {
        float pr = fmaf(sr[r], sr[r], si[r] * si[r]);
        P += pr;
        #pragma unroll
        for (int k = 0; k < 4; ++k)
            pk[k] += ((r >> k) & 1) ? -pr : pr;
    }
    #pragma unroll
    for (int k = 4; k < NCL; ++k)
        pk[k] = ((lane >> (k - 4)) & 1) ? -P : P;
    #pragma unroll
    for (int k = 0; k < NCL; ++k) {
        float v = pk[k];
        #pragma unroll
        for (int m = 1; m < 64; m <<= 1)
            v += __shfl_xor(v, m);
        pk[k] = v;   // all lanes now hold q_k
    }

    if (lane < NCL) {
        float o = b_post[lane];
        #pragma unroll
        for (int k = 0; k < NCL; ++k)
            o = fmaf(pk[k], W_post[lane * NQ + k], o);
        out[b * NCL + lane] = o;
    }
}

extern "C" void kernel_launch(void* const* d_in, const int* in_sizes, int n_in,
                              void* d_out, int out_size, void* d_ws, size_t ws_size,
                              hipStream_t stream) {
    const float* x       = (const float*)d_in[0];
    const float* W_pre   = (const float*)d_in[1];
    const float* b_pre   = (const float*)d_in[2];
    const float* weights = (const float*)d_in[3];
    const float* W_post  = (const float*)d_in[4];
    const float* b_post  = (const float*)d_in[5];
    float* outp = (float*)d_out;
    int batch = in_sizes[0] / NQ;
    int grid = (batch + 3) / 4;
    qnn_kernel<<<grid, 256, 0, stream>>>(x, W_pre, b_pre, weights, W_post, b_post, outp, batch);
}

// Round 5
// 30.385 us; speedup vs baseline: 1.3316x; 1.1385x over previous
//
#include <hip/hip_runtime.h>

#define NQ   10
#define NL   4
#define NCL  10
#define PI_F 3.14159265358979f

// Broadcast lane l's value to all lanes via v_readlane (no DS pipe).
__device__ __forceinline__ float bcastf(float v, int l) {
    return __int_as_float(__builtin_amdgcn_readlane(__float_as_int(v), l));
}

// Cross-lane xor-butterfly fetch on the VALU pipe where possible.
template<int M>
__device__ __forceinline__ float xlane(float v) {
    if constexpr (M == 1) {        // quad_perm [1,0,3,2]
        return __int_as_float(__builtin_amdgcn_update_dpp(
            __float_as_int(v), __float_as_int(v), 0xB1, 0xF, 0xF, false));
    } else if constexpr (M == 2) { // quad_perm [2,3,0,1]
        return __int_as_float(__builtin_amdgcn_update_dpp(
            __float_as_int(v), __float_as_int(v), 0x4E, 0xF, 0xF, false));
    } else if constexpr (M == 8) { // row_ror:8 == xor 8 within 16-lane rows
        return __int_as_float(__builtin_amdgcn_update_dpp(
            __float_as_int(v), __float_as_int(v), 0x128, 0xF, 0xF, false));
    } else if constexpr (M == 16) {
#if __has_builtin(__builtin_amdgcn_permlane16_swap)
        // res = {vdst', vsrc'}; at every lane exactly one of them is bitwise-own.
        auto r = __builtin_amdgcn_permlane16_swap(
            (unsigned)__float_as_int(v), (unsigned)__float_as_int(v), false, false);
        return __int_as_float((int)(r[0] ^ r[1] ^ (unsigned)__float_as_int(v)));
#else
        return __shfl_xor(v, 16);
#endif
    } else if constexpr (M == 32) {
#if __has_builtin(__builtin_amdgcn_permlane32_swap)
        auto r = __builtin_amdgcn_permlane32_swap(
            (unsigned)__float_as_int(v), (unsigned)__float_as_int(v), false, false);
        return __int_as_float((int)(r[0] ^ r[1] ^ (unsigned)__float_as_int(v)));
#else
        return __shfl_xor(v, 32);
#endif
    } else {                       // M == 4: no symmetric DPP pattern — DS swizzle
        return __shfl_xor(v, M);
    }
}

// RY butterfly on a lane-bit wire: a' = c*a + se*partner, se = own_bit ? +s : -s.
template<int M>
__device__ __forceinline__ void xwire(float c, float s, int lane,
                                      float (&sr)[16], float (&si)[16]) {
    const float se = (lane & M) ? s : -s;
    #pragma unroll
    for (int r = 0; r < 16; ++r) {
        float tr = xlane<M>(sr[r]);
        float ti = xlane<M>(si[r]);
        sr[r] = fmaf(c, sr[r], se * tr);
        si[r] = fmaf(c, si[r], se * ti);
    }
}

// Layout: one wave per batch element. Lane l holds amplitudes d = (l<<4)|r:
// register bits = qubits 0..3, lane bits = qubits 4..9.
__global__ __launch_bounds__(256)
void qnn_kernel(const float* __restrict__ x,
                const float* __restrict__ W_pre,
                const float* __restrict__ b_pre,
                const float* __restrict__ weights,
                const float* __restrict__ W_post,
                const float* __restrict__ b_post,
                float* __restrict__ out, int batch)
{
    const int lane = threadIdx.x & 63;
    const int b = blockIdx.x * 4 + (threadIdx.x >> 6);
    if (b >= batch) return;

    // 50 half-angle cos/sin pairs: lane j<50 owns weight j.
    float cw = 0.0f, sw = 0.0f;
    if (lane < (NL + 1) * NQ) {
        float th = 0.5f * weights[lane];
        sincosf(th, &sw, &cw);
    }

    // h = x @ W_pre.T + b_pre : lane j<10 computes h_j.
    float hval = 0.0f;
    if (lane < NQ) {
        hval = b_pre[lane];
        #pragma unroll
        for (int k = 0; k < NQ; ++k)
            hval = fmaf(x[b * NQ + k], W_pre[lane * NQ + k], hval);
    }
    float h[NQ];
    #pragma unroll
    for (int i = 0; i < NQ; ++i) h[i] = bcastf(hval, i);
    float z[NQ - 1];
    #pragma unroll
    for (int i = 0; i < NQ - 1; ++i) z[i] = (PI_F - h[i]) * (PI_F - h[i + 1]);

    // State init: (1/32) * exp(-i*ang(d)).
    float A = 0.0f;
    #pragma unroll
    for (int i = 4; i < NQ; ++i)
        A += ((lane >> (i - 4)) & 1) ? -h[i] : h[i];
    #pragma unroll
    for (int i = 4; i < NQ - 1; ++i)
        A += (((lane >> (i - 4)) ^ (lane >> (i - 3))) & 1) ? -z[i] : z[i];

    float sr[16], si[16];
    #pragma unroll
    for (int r = 0; r < 16; ++r) {
        float ang = A;
        #pragma unroll
        for (int i = 0; i < 4; ++i)
            ang += ((r >> i) & 1) ? -h[i] : h[i];
        #pragma unroll
        for (int i = 0; i < 3; ++i)
            ang += (((r >> i) ^ (r >> (i + 1))) & 1) ? -z[i] : z[i];
        ang += (((r >> 3) ^ lane) & 1) ? -z[3] : z[3];
        float sn, cn;
        __sincosf(ang, &sn, &cn);
        sr[r] = 0.03125f * cn;
        si[r] = -0.03125f * sn;
    }

    // Composite CNOT-chain perm, lane part: l' = ((l ^ (l<<1)) & 0x3F) ^ r3
    const int plbase = (lane ^ (lane << 1)) & 0x3F;

    #pragma unroll
    for (int l = 0; l <= NL; ++l) {
        if (l > 0) {
            // new[(l,r)] = old[(l', r')], r' = (r ^ (r<<1)) & 0xF
            float nr[16], ni[16];
            #pragma unroll
            for (int r = 0; r < 16; ++r) {
                const int rp = (r ^ (r << 1)) & 0xF;
                const int sl = plbase ^ (r >> 3);
                nr[r] = __shfl(sr[rp], sl);
                ni[r] = __shfl(si[rp], sl);
            }
            #pragma unroll
            for (int r = 0; r < 16; ++r) { sr[r] = nr[r]; si[r] = ni[r]; }
        }

        // RY wires 0..3: in-register butterflies.
        #pragma unroll
        for (int w = 0; w < 4; ++w) {
            const float c = bcastf(cw, l * NQ + w);
            const float s = bcastf(sw, l * NQ + w);
            #pragma unroll
            for (int r = 0; r < 16; ++r) {
                if (r & (1 << w)) continue;
                const int q = r | (1 << w);
                float a0 = sr[r], a1 = sr[q];
                sr[r] = fmaf(c, a0, -(s * a1));
                sr[q] = fmaf(s, a0, c * a1);
                float b0 = si[r], b1 = si[q];
                si[r] = fmaf(c, b0, -(s * b1));
                si[q] = fmaf(s, b0, c * b1);
            }
        }

        // RY wires 4..9: lane-bit butterflies (DPP / permlane / swizzle).
        xwire<1 >(bcastf(cw, l * NQ + 4), bcastf(sw, l * NQ + 4), lane, sr, si);
        xwire<2 >(bcastf(cw, l * NQ + 5), bcastf(sw, l * NQ + 5), lane, sr, si);
        xwire<4 >(bcastf(cw, l * NQ + 6), bcastf(sw, l * NQ + 6), lane, sr, si);
        xwire<8 >(bcastf(cw, l * NQ + 7), bcastf(sw, l * NQ + 7), lane, sr, si);
        xwire<16>(bcastf(cw, l * NQ + 8), bcastf(sw, l * NQ + 8), lane, sr, si);
        xwire<32>(bcastf(cw, l * NQ + 9), bcastf(sw, l * NQ + 9), lane, sr, si);
    }

    // q_k = sum_d p(d) * (1 - 2*bit_k(d)).
    float P = 0.0f;
    float pk[NCL];
    #pragma unroll
    for (int k = 0; k < 4; ++k) pk[k] = 0.0f;
    #pragma unroll
    for (int r = 0; r < 16; ++r) {
        float pr = fmaf(sr[r], sr[r], si[r] * si[r]);
        P += pr;
        #pragma unroll
        for (int k = 0; k < 4; ++k)
            pk[k] += ((r >> k) & 1) ? -pr : pr;
    }
    #pragma unroll
    for (int k = 4; k < NCL; ++k)
        pk[k] = ((lane >> (k - 4)) & 1) ? -P : P;
    #pragma unroll
    for (int k = 0; k < NCL; ++k) {
        float v = pk[k];
        v += xlane<1>(v);
        v += xlane<2>(v);
        v += xlane<4>(v);
        v += xlane<8>(v);
        v += xlane<16>(v);
        v += xlane<32>(v);
        pk[k] = v;
    }

    if (lane < NCL) {
        float o = b_post[lane];
        #pragma unroll
        for (int k = 0; k < NCL; ++k)
            o = fmaf(pk[k], W_post[lane * NQ + k], o);
        out[b * NCL + lane] = o;
    }
}

extern "C" void kernel_launch(void* const* d_in, const int* in_sizes, int n_in,
                              void* d_out, int out_size, void* d_ws, size_t ws_size,
                              hipStream_t stream) {
    const float* x       = (const float*)d_in[0];
    const float* W_pre   = (const float*)d_in[1];
    const float* b_pre   = (const float*)d_in[2];
    const float* weights = (const float*)d_in[3];
    const float* W_post  = (const float*)d_in[4];
    const float* b_post  = (const float*)d_in[5];
    float* outp = (float*)d_out;
    int batch = in_sizes[0] / NQ;
    int grid = (batch + 3) / 4;
    qnn_kernel<<<grid, 256, 0, stream>>>(x, W_pre, b_pre, weights, W_post, b_post, outp, batch);
}

// Round 6
// 28.934 us; speedup vs baseline: 1.3984x; 1.0502x over previous
//
#include <hip/hip_runtime.h>

#define NQ   10
#define NL   4
#define NCL  10
#define PI_F 3.14159265358979f

// Broadcast lane l's value to all lanes via v_readlane (l may be runtime-uniform).
__device__ __forceinline__ float bcastf(float v, int l) {
    return __int_as_float(__builtin_amdgcn_readlane(__float_as_int(v), l));
}

// Cross-lane xor-butterfly fetch. VALU (DPP/permlane) where possible,
// imm-pattern ds_swizzle for m=4 (no address math).
template<int M>
__device__ __forceinline__ float xlane(float v) {
    if constexpr (M == 1) {        // quad_perm [1,0,3,2]
        return __int_as_float(__builtin_amdgcn_update_dpp(
            __float_as_int(v), __float_as_int(v), 0xB1, 0xF, 0xF, false));
    } else if constexpr (M == 2) { // quad_perm [2,3,0,1]
        return __int_as_float(__builtin_amdgcn_update_dpp(
            __float_as_int(v), __float_as_int(v), 0x4E, 0xF, 0xF, false));
    } else if constexpr (M == 4) { // ds_swizzle xor-4, imm pattern
        return __int_as_float(__builtin_amdgcn_ds_swizzle(
            __float_as_int(v), 0x101F));
    } else if constexpr (M == 8) { // row_ror:8 == xor-8 within 16-lane rows
        return __int_as_float(__builtin_amdgcn_update_dpp(
            __float_as_int(v), __float_as_int(v), 0x128, 0xF, 0xF, false));
    } else if constexpr (M == 16) {
        // direction-proof: one of the two results is bitwise-own at every lane
        auto r = __builtin_amdgcn_permlane16_swap(
            (unsigned)__float_as_int(v), (unsigned)__float_as_int(v), false, false);
        return __int_as_float((int)(r[0] ^ r[1] ^ (unsigned)__float_as_int(v)));
    } else {                       // M == 32
        auto r = __builtin_amdgcn_permlane32_swap(
            (unsigned)__float_as_int(v), (unsigned)__float_as_int(v), false, false);
        return __int_as_float((int)(r[0] ^ r[1] ^ (unsigned)__float_as_int(v)));
    }
}

// RY butterfly on a lane-bit wire: a' = c*a + se*partner, se = own_bit ? +s : -s.
template<int M>
__device__ __forceinline__ void xwire(float c, float s, int lane,
                                      float (&sr)[16], float (&si)[16]) {
    const float se = (lane & M) ? s : -s;
    #pragma unroll
    for (int r = 0; r < 16; ++r) {
        float tr = xlane<M>(sr[r]);
        float ti = xlane<M>(si[r]);
        sr[r] = fmaf(c, sr[r], se * tr);
        si[r] = fmaf(c, si[r], se * ti);
    }
}

// Layout: one wave per batch element. Lane l holds amplitudes d = (l<<4)|r:
// register bits = qubits 0..3, lane bits = qubits 4..9.
__global__ __launch_bounds__(256)
void qnn_kernel(const float* __restrict__ x,
                const float* __restrict__ W_pre,
                const float* __restrict__ b_pre,
                const float* __restrict__ weights,
                const float* __restrict__ W_post,
                const float* __restrict__ b_post,
                float* __restrict__ out, int batch)
{
    const int lane = threadIdx.x & 63;
    const int b = blockIdx.x * 4 + (threadIdx.x >> 6);
    if (b >= batch) return;

    // 50 half-angle cos/sin pairs: lane j<50 owns weight j.
    float cw = 0.0f, sw = 0.0f;
    if (lane < (NL + 1) * NQ) {
        float th = 0.5f * weights[lane];
        __sincosf(th, &sw, &cw);
    }

    // h = x @ W_pre.T + b_pre : lane j<10 computes h_j.
    float hval = 0.0f;
    if (lane < NQ) {
        hval = b_pre[lane];
        #pragma unroll
        for (int k = 0; k < NQ; ++k)
            hval = fmaf(x[b * NQ + k], W_pre[lane * NQ + k], hval);
    }
    float h[NQ];
    #pragma unroll
    for (int i = 0; i < NQ; ++i) h[i] = bcastf(hval, i);
    float z[NQ - 1];
    #pragma unroll
    for (int i = 0; i < NQ - 1; ++i) z[i] = (PI_F - h[i]) * (PI_F - h[i + 1]);

    // State init: (1/32) * exp(-i*ang(d)).
    float A = 0.0f;
    #pragma unroll
    for (int i = 4; i < NQ; ++i)
        A += ((lane >> (i - 4)) & 1) ? -h[i] : h[i];
    #pragma unroll
    for (int i = 4; i < NQ - 1; ++i)
        A += (((lane >> (i - 4)) ^ (lane >> (i - 3))) & 1) ? -z[i] : z[i];

    float sr[16], si[16];
    #pragma unroll
    for (int r = 0; r < 16; ++r) {
        float ang = A;
        #pragma unroll
        for (int i = 0; i < 4; ++i)
            ang += ((r >> i) & 1) ? -h[i] : h[i];
        #pragma unroll
        for (int i = 0; i < 3; ++i)
            ang += (((r >> i) ^ (r >> (i + 1))) & 1) ? -z[i] : z[i];
        ang += (((r >> 3) ^ lane) & 1) ? -z[3] : z[3];
        float sn, cn;
        __sincosf(ang, &sn, &cn);
        sr[r] = 0.03125f * cn;
        si[r] = -0.03125f * sn;
    }

    // Composite CNOT-chain perm, lane part: l' = ((l ^ (l<<1)) & 0x3F) ^ r3.
    // Precompute both bpermute byte-addresses once.
    const int plbase = (lane ^ (lane << 1)) & 0x3F;
    const int paddr0 = plbase << 2;
    const int paddr1 = (plbase ^ 1) << 2;

    // Rolled layer loop: body fits I-cache, reused 5x.
    #pragma clang loop unroll(disable)
    for (int l = 0; l <= NL; ++l) {
        if (l > 0) {
            // new[(l,r)] = old[(l', r')], r' = (r ^ (r<<1)) & 0xF
            float nr[16], ni[16];
            #pragma unroll
            for (int r = 0; r < 16; ++r) {
                const int rp = (r ^ (r << 1)) & 0xF;
                const int pa = (r < 8) ? paddr0 : paddr1;
                nr[r] = __int_as_float(__builtin_amdgcn_ds_bpermute(pa, __float_as_int(sr[rp])));
                ni[r] = __int_as_float(__builtin_amdgcn_ds_bpermute(pa, __float_as_int(si[rp])));
            }
            #pragma unroll
            for (int r = 0; r < 16; ++r) { sr[r] = nr[r]; si[r] = ni[r]; }
        }

        const int base = l * NQ;

        // RY wires 0..3: in-register butterflies.
        #pragma unroll
        for (int w = 0; w < 4; ++w) {
            const float c = bcastf(cw, base + w);
            const float s = bcastf(sw, base + w);
            #pragma unroll
            for (int r = 0; r < 16; ++r) {
                if (r & (1 << w)) continue;
                const int q = r | (1 << w);
                float a0 = sr[r], a1 = sr[q];
                sr[r] = fmaf(c, a0, -(s * a1));
                sr[q] = fmaf(s, a0, c * a1);
                float b0 = si[r], b1 = si[q];
                si[r] = fmaf(c, b0, -(s * b1));
                si[q] = fmaf(s, b0, c * b1);
            }
        }

        // RY wires 4..9: lane-bit butterflies.
        xwire<1 >(bcastf(cw, base + 4), bcastf(sw, base + 4), lane, sr, si);
        xwire<2 >(bcastf(cw, base + 5), bcastf(sw, base + 5), lane, sr, si);
        xwire<4 >(bcastf(cw, base + 6), bcastf(sw, base + 6), lane, sr, si);
        xwire<8 >(bcastf(cw, base + 7), bcastf(sw, base + 7), lane, sr, si);
        xwire<16>(bcastf(cw, base + 8), bcastf(sw, base + 8), lane, sr, si);
        xwire<32>(bcastf(cw, base + 9), bcastf(sw, base + 9), lane, sr, si);
    }

    // q_k = sum_d p(d) * (1 - 2*bit_k(d)).
    float P = 0.0f;
    float pk[NCL];
    #pragma unroll
    for (int k = 0; k < 4; ++k) pk[k] = 0.0f;
    #pragma unroll
    for (int r = 0; r < 16; ++r) {
        float pr = fmaf(sr[r], sr[r], si[r] * si[r]);
        P += pr;
        #pragma unroll
        for (int k = 0; k < 4; ++k)
            pk[k] += ((r >> k) & 1) ? -pr : pr;
    }
    #pragma unroll
    for (int k = 4; k < NCL; ++k)
        pk[k] = ((lane >> (k - 4)) & 1) ? -P : P;
    #pragma unroll
    for (int k = 0; k < NCL; ++k) {
        float v = pk[k];
        v += xlane<1>(v);
        v += xlane<2>(v);
        v += xlane<4>(v);
        v += xlane<8>(v);
        v += xlane<16>(v);
        v += xlane<32>(v);
        pk[k] = v;
    }

    if (lane < NCL) {
        float o = b_post[lane];
        #pragma unroll
        for (int k = 0; k < NCL; ++k)
            o = fmaf(pk[k], W_post[lane * NQ + k], o);
        out[b * NCL + lane] = o;
    }
}

extern "C" void kernel_launch(void* const* d_in, const int* in_sizes, int n_in,
                              void* d_out, int out_size, void* d_ws, size_t ws_size,
                              hipStream_t stream) {
    const float* x       = (const float*)d_in[0];
    const float* W_pre   = (const float*)d_in[1];
    const float* b_pre   = (const float*)d_in[2];
    const float* weights = (const float*)d_in[3];
    const float* W_post  = (const float*)d_in[4];
    const float* b_post  = (const float*)d_in[5];
    float* outp = (float*)d_out;
    int batch = in_sizes[0] / NQ;
    int grid = (batch + 3) / 4;
    qnn_kernel<<<grid, 256, 0, stream>>>(x, W_pre, b_pre, weights, W_post, b_post, outp, batch);
}